// Round 6
// baseline (1176.183 us; speedup 1.0000x reference)
//
#include <hip/hip_runtime.h>

#define BATCH 4
#define NPTS  4096
#define NC    1024
#define KNN   32
#define CIN   128
#define CO    256
#define DP    136   // padded feature dim; pad entries exact zeros

// output layout (flat f32, reference return order)
#define OFF_CXYZ 0
#define OFF_CMAD (BATCH*NC*3)
#define OFF_CADJ (OFF_CMAD + BATCH*NC*3)
#define OFF_CPT  (OFF_CADJ + BATCH*NC*2)
#define OFF_OMAD (OFF_CPT  + BATCH*NC*4)
#define OFF_OADJ (OFF_OMAD + BATCH*NC*CO)
#define OFF_OPT  (OFF_OADJ + BATCH*NC*CO)
#define OFF_OCST (OFF_OPT  + BATCH*NC*CO)

typedef unsigned long long u64;

// ---------------------------------------------------------------------------
// u64 wave-64 reduce via DPP (VALU pipe). Result valid in lane 63.
// ---------------------------------------------------------------------------
template<bool MAXI>
__device__ __forceinline__ u64 wave_red_u64(u64 k)
{
    const int oldv = MAXI ? 0 : -1;
#define DPP_STEP(C)                                                              \
    {                                                                            \
        unsigned plo = (unsigned)__builtin_amdgcn_update_dpp(oldv, (int)(unsigned)k,        C, 0xf, 0xf, false); \
        unsigned phi = (unsigned)__builtin_amdgcn_update_dpp(oldv, (int)(unsigned)(k>>32),  C, 0xf, 0xf, false); \
        u64 p = ((u64)phi << 32) | plo;                                          \
        if (MAXI ? (p > k) : (p < k)) k = p;                                     \
    }
    DPP_STEP(0x111) DPP_STEP(0x112) DPP_STEP(0x114)
    DPP_STEP(0x118) DPP_STEP(0x142) DPP_STEP(0x143)
#undef DPP_STEP
    return k;
}

// ---------------------------------------------------------------------------
// Fused kernel: blocks 0..3 run FPS at 512 threads x 8 pts; blocks 4..547
// precompute M[type] = Wq·Wk^T (zero-padded) and padded Wvp on idle CUs.
// ---------------------------------------------------------------------------
__global__ __launch_bounds__(512) void fps_prep_kernel(
    const float* __restrict__ xyz, int* __restrict__ fps_idx,
    const float* __restrict__ wq_mad, const float* __restrict__ wk_mad, const float* __restrict__ wv_mad,
    const float* __restrict__ wq_adj, const float* __restrict__ wk_adj, const float* __restrict__ wv_adj,
    const float* __restrict__ wq_pt,  const float* __restrict__ wk_pt,  const float* __restrict__ wv_pt,
    const float* __restrict__ wq_cst, const float* __restrict__ wk_cst, const float* __restrict__ wv_cst,
    float* __restrict__ M, float* __restrict__ Wvp)
{
    __shared__ float4 s_xyz[NPTS];          // 64 KB (prep reuses as scratch)
    __shared__ u64    s_ck[2][8];
    const int t = threadIdx.x;

    if (blockIdx.x >= BATCH) {
        // ---------------- prep path ----------------
        const int r    = blockIdx.x - BATCH;   // 0..4*DP-1
        const int type = r / DP;
        const int row  = r - type * DP;
        const float* wq; const float* wk; const float* wv; int D;
        if (type == 0)      { wq=wq_mad; wk=wk_mad; wv=wv_mad; D=131; }
        else if (type == 1) { wq=wq_adj; wk=wk_adj; wv=wv_adj; D=132; }
        else if (type == 2) { wq=wq_pt;  wk=wk_pt;  wv=wv_pt;  D=136; }
        else                { wq=wq_cst; wk=wk_cst; wv=wv_cst; D=131; }

        if (t < CO)
            Wvp[((size_t)type*DP + row)*CO + t] = (row < D) ? wv[(size_t)row*CO + t] : 0.f;

        if (row < CIN) {
            float* sq = (float*)s_xyz;
            if (t < CO) sq[t] = wq[(size_t)row*CO + t];
            __syncthreads();
            if (t < DP) {
                float acc = 0.f;
                if (t < D) {
                    const float* wkr = wk + (size_t)t * CO;
                    for (int h = 0; h < CO; h += 4) {
                        float4 a = *(const float4*)&wkr[h];
                        float4 b4 = *(const float4*)&sq[h];
                        acc = fmaf(a.x,b4.x,acc); acc = fmaf(a.y,b4.y,acc);
                        acc = fmaf(a.z,b4.z,acc); acc = fmaf(a.w,b4.w,acc);
                    }
                }
                M[((size_t)type*CIN + row)*DP + t] = acc;
            }
        }
        return;
    }

    // ---------------- FPS path: 512 threads x 8 points ----------------
    const int b = blockIdx.x;
    const float* xb = xyz + (size_t)b * NPTS * 3;

    float px[8], py[8], pz[8], dd[8];
    unsigned inv[8];
#pragma unroll
    for (int i = 0; i < 8; ++i) {
        int p = t + i * 512;
        px[i] = xb[p*3+0]; py[i] = xb[p*3+1]; pz[i] = xb[p*3+2];
        s_xyz[p] = make_float4(px[i], py[i], pz[i], 0.f);
        dd[i] = 1e10f;
        inv[i] = ~(unsigned)p;
    }
    __syncthreads();

    int far = 0;
    float cx = xb[0], cy = xb[1], cz = xb[2];
    for (int s = 0; s < NC; ++s) {
        if (t == 0) fps_idx[b*NC + s] = far;
        u64 K[8];
#pragma unroll
        for (int i = 0; i < 8; ++i) {
            float dx = __fsub_rn(px[i], cx);
            float dy = __fsub_rn(py[i], cy);
            float dz = __fsub_rn(pz[i], cz);
            float d  = __fadd_rn(__fadd_rn(__fmul_rn(dx,dx), __fmul_rn(dy,dy)), __fmul_rn(dz,dz));
            float nd = fminf(dd[i], d);
            dd[i] = nd;
            K[i] = ((u64)__float_as_uint(nd) << 32) | inv[i];   // dd>=0 => bits monotonic
        }
#pragma unroll
        for (int st = 4; st >= 1; st >>= 1)
#pragma unroll
            for (int j = 0; j < st; ++j)
                if (K[j+st] > K[j]) K[j] = K[j+st];
        u64 k = wave_red_u64<true>(K[0]);

        const int buf = s & 1;
        if ((t & 63) == 63) s_ck[buf][t>>6] = k;
        __syncthreads();
        u64 c0 = s_ck[buf][0], c1 = s_ck[buf][1], c2 = s_ck[buf][2], c3 = s_ck[buf][3];
        u64 c4 = s_ck[buf][4], c5 = s_ck[buf][5], c6 = s_ck[buf][6], c7 = s_ck[buf][7];
        if (c1 > c0) c0 = c1;  if (c3 > c2) c2 = c3;
        if (c5 > c4) c4 = c5;  if (c7 > c6) c6 = c7;
        if (c2 > c0) c0 = c2;  if (c6 > c4) c4 = c6;
        if (c4 > c0) c0 = c4;
        far = (int)~((unsigned)c0);
        float4 c = s_xyz[far];
        cx = c.x; cy = c.y; cz = c.z;
    }
}

// ---------------------------------------------------------------------------
// Attention phases (round-5 verified) — unchanged math/op order.
// ---------------------------------------------------------------------------
template<int TYPE>
__device__ __forceinline__ void attn_t(
    int b, int bs0, int ci,
    const float* __restrict__ fea, const float* __restrict__ aux,
    const float* __restrict__ Mt, const float* __restrict__ Wvpt,
    float* __restrict__ outp,
    float (*s_cf)[CIN], float (*s_u)[DP], float (*s_fea)[KNN][DP],
    float (*s_sc)[KNN], float (*s_wf)[DP], const int (*s_nbr4)[KNN])
{
    const int t = threadIdx.x, g = t >> 6, l = t & 63;
    const int l31 = l & 31, h32 = l >> 5;

    // ---- stage (wave-private to center g) ----
    if (l < 32) {
        float4 v = *(const float4*)&fea[((size_t)(b*NPTS + ci))*CIN + l*4];
        *(float4*)&s_cf[g][l*4] = v;
    }
#pragma unroll
    for (int it = 0; it < 16; ++it) {
        int kk = it*2 + h32;
        int j  = s_nbr4[g][kk];
        float4 v = *(const float4*)&fea[((size_t)(b*NPTS + j))*CIN + l31*4];
        *(float4*)&s_fea[g][kk][l31*4] = v;
    }
    if (l < KNN) {
        int j = s_nbr4[g][l];
        float pad[8];
        if (TYPE == 0 || TYPE == 3) {
#pragma unroll
            for (int i = 0; i < 3; ++i)
                pad[i] = aux[(size_t)(b*NPTS + j)*3 + i] - aux[(size_t)(b*NPTS + ci)*3 + i];
            pad[3]=pad[4]=pad[5]=pad[6]=pad[7]=0.f;
        } else if (TYPE == 1) {
            pad[0] = aux[(size_t)(b*NPTS + j)*2 + 0];
            pad[1] = aux[(size_t)(b*NPTS + j)*2 + 1];
            pad[2] = aux[(size_t)(b*NPTS + ci)*2 + 0];
            pad[3] = aux[(size_t)(b*NPTS + ci)*2 + 1];
            pad[4]=pad[5]=pad[6]=pad[7]=0.f;
        } else {
#pragma unroll
            for (int i = 0; i < 4; ++i) pad[i]   = aux[(size_t)(b*NPTS + j)*4 + i];
#pragma unroll
            for (int i = 0; i < 4; ++i) pad[4+i] = aux[(size_t)(b*NPTS + ci)*4 + i];
        }
#pragma unroll
        for (int i = 0; i < 8; ++i) s_fea[g][l][CIN+i] = pad[i];
    }
    __syncthreads();

    // ---- u[g][d] = sum_c cf[g][c] * M[c][d] ----
#pragma unroll
    for (int j = 0; j < 3; ++j) {
        int d = l + 64*j;
        if (d < DP) {
            float acc = 0.f;
            for (int c = 0; c < CIN; c += 4) {
                float4 cf4 = *(const float4*)&s_cf[g][c];
                acc = fmaf(cf4.x, Mt[(size_t)(c+0)*DP + d], acc);
                acc = fmaf(cf4.y, Mt[(size_t)(c+1)*DP + d], acc);
                acc = fmaf(cf4.z, Mt[(size_t)(c+2)*DP + d], acc);
                acc = fmaf(cf4.w, Mt[(size_t)(c+3)*DP + d], acc);
            }
            s_u[g][d] = acc;
        }
    }
    __syncthreads();

    // ---- scores[g][kk] = (u[g] . fea[g][kk]) / 16 ----
#pragma unroll
    for (int it = 0; it < 16; ++it) {
        int kk = it*2 + h32;
        float acc = 0.f;
        for (int c = l31; c < DP/4; c += 32) {
            float4 f4 = *(const float4*)&s_fea[g][kk][c*4];
            float4 u4 = *(const float4*)&s_u[g][c*4];
            acc = fmaf(f4.x,u4.x,acc); acc = fmaf(f4.y,u4.y,acc);
            acc = fmaf(f4.z,u4.z,acc); acc = fmaf(f4.w,u4.w,acc);
        }
#pragma unroll
        for (int off = 16; off; off >>= 1) acc += __shfl_xor(acc, off);
        if (l31 == 0) s_sc[g][kk] = acc * 0.0625f;
    }
    __syncthreads();

    // ---- softmax over 32 ----
    if (l < KNN) {
        float sc = s_sc[g][l];
        float m = sc;
#pragma unroll
        for (int off = 16; off; off >>= 1) m = fmaxf(m, __shfl_xor(m, off));
        float e = expf(sc - m);
        float ssum = e;
#pragma unroll
        for (int off = 16; off; off >>= 1) ssum += __shfl_xor(ssum, off);
        s_sc[g][l] = e / ssum;
    }
    __syncthreads();

    // ---- wfea[g][d] = sum_k attn[g][k] * fea[g][k][d] ----
    if (l < DP/4) {
        const int d0 = l*4;
        float w0=0.f, w1=0.f, w2=0.f, w3=0.f;
#pragma unroll
        for (int k4 = 0; k4 < KNN; k4 += 4) {
            float4 a  = *(const float4*)&s_sc[g][k4];
            float4 f0 = *(const float4*)&s_fea[g][k4+0][d0];
            float4 f1 = *(const float4*)&s_fea[g][k4+1][d0];
            float4 f2 = *(const float4*)&s_fea[g][k4+2][d0];
            float4 f3 = *(const float4*)&s_fea[g][k4+3][d0];
            w0=fmaf(a.x,f0.x,w0); w1=fmaf(a.x,f0.y,w1); w2=fmaf(a.x,f0.z,w2); w3=fmaf(a.x,f0.w,w3);
            w0=fmaf(a.y,f1.x,w0); w1=fmaf(a.y,f1.y,w1); w2=fmaf(a.y,f1.z,w2); w3=fmaf(a.y,f1.w,w3);
            w0=fmaf(a.z,f2.x,w0); w1=fmaf(a.z,f2.y,w1); w2=fmaf(a.z,f2.z,w2); w3=fmaf(a.z,f2.w,w3);
            w0=fmaf(a.w,f3.x,w0); w1=fmaf(a.w,f3.y,w1); w2=fmaf(a.w,f3.z,w2); w3=fmaf(a.w,f3.w,w3);
        }
        s_wf[g][d0+0]=w0; s_wf[g][d0+1]=w1; s_wf[g][d0+2]=w2; s_wf[g][d0+3]=w3;
    }
    __syncthreads();

    // ---- o[g][h=t] = sum_d wf[g][d] * Wvp[d][h] ----
    float o0=0.f, o1=0.f, o2=0.f, o3=0.f;
    for (int d4 = 0; d4 < DP/4; ++d4) {
        float4 wf0 = *(const float4*)&s_wf[0][d4*4];
        float4 wf1 = *(const float4*)&s_wf[1][d4*4];
        float4 wf2 = *(const float4*)&s_wf[2][d4*4];
        float4 wf3 = *(const float4*)&s_wf[3][d4*4];
        float v0 = Wvpt[(size_t)(d4*4+0)*CO + t];
        float v1 = Wvpt[(size_t)(d4*4+1)*CO + t];
        float v2 = Wvpt[(size_t)(d4*4+2)*CO + t];
        float v3 = Wvpt[(size_t)(d4*4+3)*CO + t];
        o0=fmaf(wf0.x,v0,o0); o0=fmaf(wf0.y,v1,o0); o0=fmaf(wf0.z,v2,o0); o0=fmaf(wf0.w,v3,o0);
        o1=fmaf(wf1.x,v0,o1); o1=fmaf(wf1.y,v1,o1); o1=fmaf(wf1.z,v2,o1); o1=fmaf(wf1.w,v3,o1);
        o2=fmaf(wf2.x,v0,o2); o2=fmaf(wf2.y,v1,o2); o2=fmaf(wf2.z,v2,o2); o2=fmaf(wf2.w,v3,o2);
        o3=fmaf(wf3.x,v0,o3); o3=fmaf(wf3.y,v1,o3); o3=fmaf(wf3.z,v2,o3); o3=fmaf(wf3.w,v3,o3);
    }
    outp[(size_t)(bs0+0)*CO + t] = o0;
    outp[(size_t)(bs0+1)*CO + t] = o1;
    outp[(size_t)(bs0+2)*CO + t] = o2;
    outp[(size_t)(bs0+3)*CO + t] = o3;
    __syncthreads();
}

// ---------------------------------------------------------------------------
// Attn kernel with FUSED wave-private kNN: wave g selects the 32 NN of its
// center with zero barriers (64 dists/lane in registers as monotonic u32
// bits; 4 cached group-min u64 keys; DPP reduce + shfl broadcast per pass;
// winner lane rescans its group of 16). Selection semantics bit-identical
// to the reference (ascending distance, lowest-index ties).
// ---------------------------------------------------------------------------
__global__ __launch_bounds__(256, 2) void attn_kernel(
    const float* __restrict__ xyz, const float* __restrict__ mad,
    const float* __restrict__ adj, const float* __restrict__ pt,
    const float* __restrict__ mad_fea, const float* __restrict__ adj_fea,
    const float* __restrict__ pt_fea,  const float* __restrict__ cst_fea,
    const float* __restrict__ M, const float* __restrict__ Wvp,
    const int* __restrict__ fps_idx,
    float* __restrict__ out)
{
    __shared__ float s_cf[4][CIN];
    __shared__ float s_u[4][DP];
    __shared__ float s_fea[4][KNN][DP];
    __shared__ float s_sc[4][KNN];
    __shared__ float s_wf[4][DP];
    __shared__ int   s_nbr4[4][KNN];

    const int bs0 = blockIdx.x * 4;
    const int b   = bs0 >> 10;
    const int t   = threadIdx.x;
    const int g   = t >> 6, l = t & 63;
    const float* xb = xyz + (size_t)b * NPTS * 3;

    const int ci = fps_idx[bs0 + g];      // wave-uniform load

    // small per-center outputs (wave-private)
    if (l < 3)             out[OFF_CXYZ + (bs0+g)*3 + l]      = xb[(size_t)ci*3 + l];
    if (l >= 4 && l < 7)   out[OFF_CMAD + (bs0+g)*3 + (l-4)]  = mad[(size_t)(b*NPTS+ci)*3 + (l-4)];
    if (l >= 8 && l < 10)  out[OFF_CADJ + (bs0+g)*2 + (l-8)]  = adj[(size_t)(b*NPTS+ci)*2 + (l-8)];
    if (l >= 12 && l < 16) out[OFF_CPT  + (bs0+g)*4 + (l-12)] = pt[(size_t)(b*NPTS+ci)*4 + (l-12)];

    // ================= fused kNN (wave-private, no barriers) =================
    {
        const float cx = xb[ci*3], cy = xb[ci*3+1], cz = xb[ci*3+2];
        const float sqc = __fadd_rn(__fadd_rn(__fmul_rn(cx,cx), __fmul_rn(cy,cy)), __fmul_rn(cz,cz));

        unsigned du[64];
#pragma unroll
        for (int j = 0; j < 64; ++j) {
            int p = l + (j << 6);
            float x = xb[p*3], y = xb[p*3+1], z = xb[p*3+2];
            float sqm = __fadd_rn(__fadd_rn(__fmul_rn(x,x), __fmul_rn(y,y)), __fmul_rn(z,z));
            float dot = __fadd_rn(__fadd_rn(__fmul_rn(cx,x), __fmul_rn(cy,y)), __fmul_rn(cz,z));
            float dv  = __fsub_rn(__fadd_rn(sqc, sqm), __fmul_rn(2.0f, dot));
            unsigned u = __float_as_uint(dv);
            u ^= (unsigned)(((int)u >> 31)) | 0x80000000u;   // order-monotonic for all floats
            du[j] = u;
        }
        u64 gk[4];
#pragma unroll
        for (int G2 = 0; G2 < 4; ++G2) {
            int j0 = G2*16;
            u64 m = ((u64)du[j0] << 32) | (unsigned)(l + (j0 << 6));
#pragma unroll
            for (int jj = 1; jj < 16; ++jj) {
                int j = j0 + jj;
                u64 kj = ((u64)du[j] << 32) | (unsigned)(l + (j << 6));
                if (kj < m) m = kj;        // ascending j => lowest idx on tie
            }
            gk[G2] = m;
        }

        for (int kk = 0; kk < KNN; ++kk) {
            u64 m01 = gk[0] < gk[1] ? gk[0] : gk[1];
            u64 m23 = gk[2] < gk[3] ? gk[2] : gk[3];
            u64 kmin = m01 < m23 ? m01 : m23;
            u64 kw = wave_red_u64<false>(kmin);
            int widx = __shfl((int)(unsigned)kw, 63);   // idx lives in low 32 bits
            if (l == 0) s_nbr4[g][kk] = widx;
            int wj = widx >> 6;
            if ((widx & 63) == l) {                     // owner lane only
#pragma unroll
                for (int G2 = 0; G2 < 4; ++G2) {
                    if ((wj >> 4) == G2) {
#pragma unroll
                        for (int jj = 0; jj < 16; ++jj)
                            if (wj == G2*16 + jj) du[G2*16 + jj] = 0xFFFFFFFFu;
                        int j0 = G2*16;
                        u64 m = ((u64)du[j0] << 32) | (unsigned)(l + (j0 << 6));
#pragma unroll
                        for (int jj = 1; jj < 16; ++jj) {
                            int j = j0 + jj;
                            u64 kj = ((u64)du[j] << 32) | (unsigned)(l + (j << 6));
                            if (kj < m) m = kj;
                        }
                        gk[G2] = m;
                    }
                }
            }
        }
    }
    // s_nbr4[g] written by wave g only; in-wave program order suffices.

    attn_t<0>(b, bs0, ci, mad_fea, mad, M + 0*CIN*DP, Wvp + 0*DP*CO, out + OFF_OMAD,
              s_cf, s_u, s_fea, s_sc, s_wf, s_nbr4);
    attn_t<1>(b, bs0, ci, adj_fea, adj, M + 1*CIN*DP, Wvp + 1*DP*CO, out + OFF_OADJ,
              s_cf, s_u, s_fea, s_sc, s_wf, s_nbr4);
    attn_t<2>(b, bs0, ci, pt_fea,  pt,  M + 2*CIN*DP, Wvp + 2*DP*CO, out + OFF_OPT,
              s_cf, s_u, s_fea, s_sc, s_wf, s_nbr4);
    attn_t<3>(b, bs0, ci, cst_fea, xyz, M + 3*CIN*DP, Wvp + 3*DP*CO, out + OFF_OCST,
              s_cf, s_u, s_fea, s_sc, s_wf, s_nbr4);
}

extern "C" void kernel_launch(void* const* d_in, const int* in_sizes, int n_in,
                              void* d_out, int out_size, void* d_ws, size_t ws_size,
                              hipStream_t stream)
{
    const float* xyz     = (const float*)d_in[0];
    const float* mad     = (const float*)d_in[1];
    const float* adj     = (const float*)d_in[2];
    const float* pt      = (const float*)d_in[3];
    const float* mad_fea = (const float*)d_in[4];
    const float* adj_fea = (const float*)d_in[5];
    const float* pt_fea  = (const float*)d_in[6];
    const float* cst_fea = (const float*)d_in[7];
    const float* wq_mad  = (const float*)d_in[8];
    const float* wk_mad  = (const float*)d_in[9];
    const float* wv_mad  = (const float*)d_in[10];
    const float* wq_adj  = (const float*)d_in[11];
    const float* wk_adj  = (const float*)d_in[12];
    const float* wv_adj  = (const float*)d_in[13];
    const float* wq_pt   = (const float*)d_in[14];
    const float* wk_pt   = (const float*)d_in[15];
    const float* wv_pt   = (const float*)d_in[16];
    const float* wq_cst  = (const float*)d_in[17];
    const float* wk_cst  = (const float*)d_in[18];
    const float* wv_cst  = (const float*)d_in[19];
    float* out = (float*)d_out;

    int*   fps_idx = (int*)d_ws;                      // 4096 ints
    float* M       = (float*)(fps_idx + BATCH*NC);    // 4*128*136 floats
    float* Wvp     = M + 4*CIN*DP;                    // 4*136*256 floats

    fps_prep_kernel<<<BATCH + 4*DP, 512, 0, stream>>>(xyz, fps_idx,
        wq_mad, wk_mad, wv_mad, wq_adj, wk_adj, wv_adj,
        wq_pt, wk_pt, wv_pt, wq_cst, wk_cst, wv_cst, M, Wvp);
    attn_kernel<<<BATCH*NC/4, 256, 0, stream>>>(xyz, mad, adj, pt,
        mad_fea, adj_fea, pt_fea, cst_fea, M, Wvp, fps_idx, out);
}

// Round 8
// 1168.961 us; speedup vs baseline: 1.0062x; 1.0062x over previous
//
#include <hip/hip_runtime.h>

#define BATCH 4
#define NPTS  4096
#define NC    1024
#define KNN   32
#define CIN   128
#define CO    256
#define DP    136   // padded feature dim; pad entries exact zeros

// output layout (flat f32, reference return order)
#define OFF_CXYZ 0
#define OFF_CMAD (BATCH*NC*3)
#define OFF_CADJ (OFF_CMAD + BATCH*NC*3)
#define OFF_CPT  (OFF_CADJ + BATCH*NC*2)
#define OFF_OMAD (OFF_CPT  + BATCH*NC*4)
#define OFF_OADJ (OFF_OMAD + BATCH*NC*CO)
#define OFF_OPT  (OFF_OADJ + BATCH*NC*CO)
#define OFF_OCST (OFF_OPT  + BATCH*NC*CO)

typedef unsigned long long u64;

// ---------------------------------------------------------------------------
// u64 wave-64 min reduce via DPP. Result valid in lane 63.
// ---------------------------------------------------------------------------
__device__ __forceinline__ u64 wave_min_u64(u64 k)
{
#define DPP_STEP(C)                                                              \
    {                                                                            \
        unsigned plo = (unsigned)__builtin_amdgcn_update_dpp(-1, (int)(unsigned)k,        C, 0xf, 0xf, false); \
        unsigned phi = (unsigned)__builtin_amdgcn_update_dpp(-1, (int)(unsigned)(k>>32),  C, 0xf, 0xf, false); \
        u64 p = ((u64)phi << 32) | plo;                                          \
        if (p < k) k = p;                                                        \
    }
    DPP_STEP(0x111) DPP_STEP(0x112) DPP_STEP(0x114)
    DPP_STEP(0x118) DPP_STEP(0x142) DPP_STEP(0x143)
#undef DPP_STEP
    return k;
}

// f32 wave max via DPP (identity -1; valid since distances >= 0). Lane 63.
__device__ __forceinline__ float wave_max_f32(float v)
{
#define DPP_STEP(C)                                                              \
    {                                                                            \
        float p = __int_as_float(__builtin_amdgcn_update_dpp(                    \
            __float_as_int(-1.0f), __float_as_int(v), C, 0xf, 0xf, false));      \
        v = fmaxf(v, p);                                                         \
    }
    DPP_STEP(0x111) DPP_STEP(0x112) DPP_STEP(0x114)
    DPP_STEP(0x118) DPP_STEP(0x142) DPP_STEP(0x143)
#undef DPP_STEP
    return v;
}

// u32 wave min via DPP (identity 0xFFFFFFFF). Lane 63.
__device__ __forceinline__ unsigned wave_min_u32(unsigned x)
{
#define DPP_STEP(C)                                                              \
    {                                                                            \
        unsigned p = (unsigned)__builtin_amdgcn_update_dpp(-1, (int)x, C, 0xf, 0xf, false); \
        x = (p < x) ? p : x;                                                     \
    }
    DPP_STEP(0x111) DPP_STEP(0x112) DPP_STEP(0x114)
    DPP_STEP(0x118) DPP_STEP(0x142) DPP_STEP(0x143)
#undef DPP_STEP
    return x;
}

// ---------------------------------------------------------------------------
// Fused kernel: blocks 0..3 run FPS (512 thr x 8 pts); blocks 4..547
// precompute M[type] = Wq·Wk^T (zero-padded) and padded Wvp on idle CUs.
// FPS loop has NO global stores (indices buffered in LDS, written at end)
// so the per-iteration barrier drains only lgkm, not vmcnt.
// Two-phase wave reduce: f32-max DPP chain, then u32-min-idx DPP chain.
// ---------------------------------------------------------------------------
__global__ __launch_bounds__(512) void fps_prep_kernel(
    const float* __restrict__ xyz, int* __restrict__ fps_idx,
    const float* __restrict__ wq_mad, const float* __restrict__ wk_mad, const float* __restrict__ wv_mad,
    const float* __restrict__ wq_adj, const float* __restrict__ wk_adj, const float* __restrict__ wv_adj,
    const float* __restrict__ wq_pt,  const float* __restrict__ wk_pt,  const float* __restrict__ wv_pt,
    const float* __restrict__ wq_cst, const float* __restrict__ wk_cst, const float* __restrict__ wv_cst,
    float* __restrict__ M, float* __restrict__ Wvp)
{
    __shared__ float4 s_xyz[NPTS];          // 64 KB (prep reuses as scratch)
    __shared__ u64    s_ck[2][8];
    __shared__ int    s_far_out[NC];        // 4 KB
    const int t = threadIdx.x;

    if (blockIdx.x >= BATCH) {
        // ---------------- prep path ----------------
        const int r    = blockIdx.x - BATCH;   // 0..4*DP-1
        const int type = r / DP;
        const int row  = r - type * DP;
        const float* wq; const float* wk; const float* wv; int D;
        if (type == 0)      { wq=wq_mad; wk=wk_mad; wv=wv_mad; D=131; }
        else if (type == 1) { wq=wq_adj; wk=wk_adj; wv=wv_adj; D=132; }
        else if (type == 2) { wq=wq_pt;  wk=wk_pt;  wv=wv_pt;  D=136; }
        else                { wq=wq_cst; wk=wk_cst; wv=wv_cst; D=131; }

        if (t < CO)
            Wvp[((size_t)type*DP + row)*CO + t] = (row < D) ? wv[(size_t)row*CO + t] : 0.f;

        if (row < CIN) {
            float* sq = (float*)s_xyz;
            if (t < CO) sq[t] = wq[(size_t)row*CO + t];
            __syncthreads();
            if (t < DP) {
                float acc = 0.f;
                if (t < D) {
                    const float* wkr = wk + (size_t)t * CO;
                    for (int h = 0; h < CO; h += 4) {
                        float4 a = *(const float4*)&wkr[h];
                        float4 b4 = *(const float4*)&sq[h];
                        acc = fmaf(a.x,b4.x,acc); acc = fmaf(a.y,b4.y,acc);
                        acc = fmaf(a.z,b4.z,acc); acc = fmaf(a.w,b4.w,acc);
                    }
                }
                M[((size_t)type*CIN + row)*DP + t] = acc;
            }
        }
        return;
    }

    // ---------------- FPS path: 512 threads x 8 points ----------------
    const int b = blockIdx.x;
    const float* xb = xyz + (size_t)b * NPTS * 3;

    float px[8], py[8], pz[8], dd[8];
#pragma unroll
    for (int i = 0; i < 8; ++i) {
        int p = t + i * 512;
        px[i] = xb[p*3+0]; py[i] = xb[p*3+1]; pz[i] = xb[p*3+2];
        s_xyz[p] = make_float4(px[i], py[i], pz[i], 0.f);
        dd[i] = 1e10f;
    }
    __syncthreads();

    int far = 0;
    float cx = xb[0], cy = xb[1], cz = xb[2];
    for (int s = 0; s < NC; ++s) {
        if (t == 0) s_far_out[s] = far;       // LDS only — no vmcnt at barrier
        float bv = -1.0f; unsigned bi = 0;
#pragma unroll
        for (int i = 0; i < 8; ++i) {
            float dx = __fsub_rn(px[i], cx);
            float dy = __fsub_rn(py[i], cy);
            float dz = __fsub_rn(pz[i], cz);
            float d  = __fadd_rn(__fadd_rn(__fmul_rn(dx,dx), __fmul_rn(dy,dy)), __fmul_rn(dz,dz));
            float nd = fminf(dd[i], d);
            dd[i] = nd;
            if (nd > bv) { bv = nd; bi = (unsigned)(t + i*512); }  // first occurrence kept
        }
        // phase A: wave max value
        float vw = wave_max_f32(bv);
        float vstar = __shfl(vw, 63);
        // phase B: wave min index among lanes matching vstar
        unsigned cand = (bv == vstar) ? bi : 0xFFFFFFFFu;
        unsigned iw = wave_min_u32(cand);

        const int buf = s & 1;
        if ((t & 63) == 63)
            s_ck[buf][t>>6] = ((u64)__float_as_uint(vstar) << 32) | (u64)(~iw);
        __syncthreads();
        u64 c0 = s_ck[buf][0], c1 = s_ck[buf][1], c2 = s_ck[buf][2], c3 = s_ck[buf][3];
        u64 c4 = s_ck[buf][4], c5 = s_ck[buf][5], c6 = s_ck[buf][6], c7 = s_ck[buf][7];
        if (c1 > c0) c0 = c1;
        if (c3 > c2) c2 = c3;
        if (c5 > c4) c4 = c5;
        if (c7 > c6) c6 = c7;
        if (c2 > c0) c0 = c2;
        if (c6 > c4) c4 = c6;      // <-- the line round 7 dropped
        if (c4 > c0) c0 = c4;
        far = (int)~((unsigned)c0);
        float4 c = s_xyz[far];
        cx = c.x; cy = c.y; cz = c.z;
    }
    __syncthreads();
    for (int i = t; i < NC; i += 512) fps_idx[b*NC + i] = s_far_out[i];
}

// ---------------------------------------------------------------------------
// kNN: wave-private, ZERO barriers. 1024 blocks x 4 waves; wave g owns
// center bs0+g. 64 dists/lane as order-monotonic u32 bits; 4 cached group-
// min u64 keys (idx embedded -> exact lowest-index ties); per pass one DPP
// min chain + shfl broadcast; winner lane rescans only its group of 16.
// ---------------------------------------------------------------------------
__global__ __launch_bounds__(256) void knn_kernel(const float* __restrict__ xyz,
                                                  const int* __restrict__ fps_idx,
                                                  int* __restrict__ nbr_idx)
{
    const int bs0 = blockIdx.x * 4;
    const int b   = bs0 >> 10;
    const int t   = threadIdx.x;
    const int g   = t >> 6, l = t & 63;
    const float* xb = xyz + (size_t)b * NPTS * 3;

    const int ci = fps_idx[bs0 + g];
    const float cx = xb[ci*3], cy = xb[ci*3+1], cz = xb[ci*3+2];
    const float sqc = __fadd_rn(__fadd_rn(__fmul_rn(cx,cx), __fmul_rn(cy,cy)), __fmul_rn(cz,cz));

    unsigned du[64];
#pragma unroll
    for (int j = 0; j < 64; ++j) {
        int p = l + (j << 6);
        float x = xb[p*3], y = xb[p*3+1], z = xb[p*3+2];
        float sqm = __fadd_rn(__fadd_rn(__fmul_rn(x,x), __fmul_rn(y,y)), __fmul_rn(z,z));
        float dot = __fadd_rn(__fadd_rn(__fmul_rn(cx,x), __fmul_rn(cy,y)), __fmul_rn(cz,z));
        float dv  = __fsub_rn(__fadd_rn(sqc, sqm), __fmul_rn(2.0f, dot));
        unsigned u = __float_as_uint(dv);
        u ^= (unsigned)(((int)u >> 31)) | 0x80000000u;   // order-monotonic for all floats
        du[j] = u;
    }
    u64 gk[4];
#pragma unroll
    for (int G = 0; G < 4; ++G) {
        int j0 = G*16;
        u64 m = ((u64)du[j0] << 32) | (unsigned)(l + (j0 << 6));
#pragma unroll
        for (int jj = 1; jj < 16; ++jj) {
            int j = j0 + jj;
            u64 kj = ((u64)du[j] << 32) | (unsigned)(l + (j << 6));
            if (kj < m) m = kj;            // ascending j => lowest idx on tie
        }
        gk[G] = m;
    }

    int* nb = nbr_idx + (size_t)(bs0 + g) * KNN;
    for (int kk = 0; kk < KNN; ++kk) {
        u64 m01 = gk[0] < gk[1] ? gk[0] : gk[1];
        u64 m23 = gk[2] < gk[3] ? gk[2] : gk[3];
        u64 kw = wave_min_u64(m01 < m23 ? m01 : m23);
        unsigned widx = (unsigned)__shfl((int)(unsigned)kw, 63);
        if (l == 0) nb[kk] = (int)widx;
        if ((widx & 63u) == (unsigned)l) {           // owner lane only
            int wj = (int)(widx >> 6);
#pragma unroll
            for (int G = 0; G < 4; ++G) {
                if ((wj >> 4) == G) {
#pragma unroll
                    for (int jj = 0; jj < 16; ++jj)
                        if (wj == G*16 + jj) du[G*16 + jj] = 0xFFFFFFFFu;
                    int j0 = G*16;
                    u64 m = ((u64)du[j0] << 32) | (unsigned)(l + (j0 << 6));
#pragma unroll
                    for (int jj = 1; jj < 16; ++jj) {
                        int j = j0 + jj;
                        u64 kj = ((u64)du[j] << 32) | (unsigned)(l + (j << 6));
                        if (kj < m) m = kj;
                    }
                    gk[G] = m;
                }
            }
        }
    }
}

// ---------------------------------------------------------------------------
// Attention phases (round-5 verified) — unchanged math/op order.
// ---------------------------------------------------------------------------
template<int TYPE>
__device__ __forceinline__ void attn_t(
    int b, int bs0, int ci,
    const float* __restrict__ fea, const float* __restrict__ aux,
    const float* __restrict__ Mt, const float* __restrict__ Wvpt,
    float* __restrict__ outp,
    float (*s_cf)[CIN], float (*s_u)[DP], float (*s_fea)[KNN][DP],
    float (*s_sc)[KNN], float (*s_wf)[DP], const int (*s_nbr4)[KNN])
{
    const int t = threadIdx.x, g = t >> 6, l = t & 63;
    const int l31 = l & 31, h32 = l >> 5;

    // ---- stage (wave-private to center g) ----
    if (l < 32) {
        float4 v = *(const float4*)&fea[((size_t)(b*NPTS + ci))*CIN + l*4];
        *(float4*)&s_cf[g][l*4] = v;
    }
#pragma unroll
    for (int it = 0; it < 16; ++it) {
        int kk = it*2 + h32;
        int j  = s_nbr4[g][kk];
        float4 v = *(const float4*)&fea[((size_t)(b*NPTS + j))*CIN + l31*4];
        *(float4*)&s_fea[g][kk][l31*4] = v;
    }
    if (l < KNN) {
        int j = s_nbr4[g][l];
        float pad[8];
        if (TYPE == 0 || TYPE == 3) {
#pragma unroll
            for (int i = 0; i < 3; ++i)
                pad[i] = aux[(size_t)(b*NPTS + j)*3 + i] - aux[(size_t)(b*NPTS + ci)*3 + i];
            pad[3]=pad[4]=pad[5]=pad[6]=pad[7]=0.f;
        } else if (TYPE == 1) {
            pad[0] = aux[(size_t)(b*NPTS + j)*2 + 0];
            pad[1] = aux[(size_t)(b*NPTS + j)*2 + 1];
            pad[2] = aux[(size_t)(b*NPTS + ci)*2 + 0];
            pad[3] = aux[(size_t)(b*NPTS + ci)*2 + 1];
            pad[4]=pad[5]=pad[6]=pad[7]=0.f;
        } else {
#pragma unroll
            for (int i = 0; i < 4; ++i) pad[i]   = aux[(size_t)(b*NPTS + j)*4 + i];
#pragma unroll
            for (int i = 0; i < 4; ++i) pad[4+i] = aux[(size_t)(b*NPTS + ci)*4 + i];
        }
#pragma unroll
        for (int i = 0; i < 8; ++i) s_fea[g][l][CIN+i] = pad[i];
    }
    __syncthreads();

    // ---- u[g][d] = sum_c cf[g][c] * M[c][d] ----
#pragma unroll
    for (int j = 0; j < 3; ++j) {
        int d = l + 64*j;
        if (d < DP) {
            float acc = 0.f;
            for (int c = 0; c < CIN; c += 4) {
                float4 cf4 = *(const float4*)&s_cf[g][c];
                acc = fmaf(cf4.x, Mt[(size_t)(c+0)*DP + d], acc);
                acc = fmaf(cf4.y, Mt[(size_t)(c+1)*DP + d], acc);
                acc = fmaf(cf4.z, Mt[(size_t)(c+2)*DP + d], acc);
                acc = fmaf(cf4.w, Mt[(size_t)(c+3)*DP + d], acc);
            }
            s_u[g][d] = acc;
        }
    }
    __syncthreads();

    // ---- scores[g][kk] = (u[g] . fea[g][kk]) / 16 ----
#pragma unroll
    for (int it = 0; it < 16; ++it) {
        int kk = it*2 + h32;
        float acc = 0.f;
        for (int c = l31; c < DP/4; c += 32) {
            float4 f4 = *(const float4*)&s_fea[g][kk][c*4];
            float4 u4 = *(const float4*)&s_u[g][c*4];
            acc = fmaf(f4.x,u4.x,acc); acc = fmaf(f4.y,u4.y,acc);
            acc = fmaf(f4.z,u4.z,acc); acc = fmaf(f4.w,u4.w,acc);
        }
#pragma unroll
        for (int off = 16; off; off >>= 1) acc += __shfl_xor(acc, off);
        if (l31 == 0) s_sc[g][kk] = acc * 0.0625f;
    }
    __syncthreads();

    // ---- softmax over 32 ----
    if (l < KNN) {
        float sc = s_sc[g][l];
        float m = sc;
#pragma unroll
        for (int off = 16; off; off >>= 1) m = fmaxf(m, __shfl_xor(m, off));
        float e = expf(sc - m);
        float ssum = e;
#pragma unroll
        for (int off = 16; off; off >>= 1) ssum += __shfl_xor(ssum, off);
        s_sc[g][l] = e / ssum;
    }
    __syncthreads();

    // ---- wfea[g][d] = sum_k attn[g][k] * fea[g][k][d] ----
    if (l < DP/4) {
        const int d0 = l*4;
        float w0=0.f, w1=0.f, w2=0.f, w3=0.f;
#pragma unroll
        for (int k4 = 0; k4 < KNN; k4 += 4) {
            float4 a  = *(const float4*)&s_sc[g][k4];
            float4 f0 = *(const float4*)&s_fea[g][k4+0][d0];
            float4 f1 = *(const float4*)&s_fea[g][k4+1][d0];
            float4 f2 = *(const float4*)&s_fea[g][k4+2][d0];
            float4 f3 = *(const float4*)&s_fea[g][k4+3][d0];
            w0=fmaf(a.x,f0.x,w0); w1=fmaf(a.x,f0.y,w1); w2=fmaf(a.x,f0.z,w2); w3=fmaf(a.x,f0.w,w3);
            w0=fmaf(a.y,f1.x,w0); w1=fmaf(a.y,f1.y,w1); w2=fmaf(a.y,f1.z,w2); w3=fmaf(a.y,f1.w,w3);
            w0=fmaf(a.z,f2.x,w0); w1=fmaf(a.z,f2.y,w1); w2=fmaf(a.z,f2.z,w2); w3=fmaf(a.z,f2.w,w3);
            w0=fmaf(a.w,f3.x,w0); w1=fmaf(a.w,f3.y,w1); w2=fmaf(a.w,f3.z,w2); w3=fmaf(a.w,f3.w,w3);
        }
        s_wf[g][d0+0]=w0; s_wf[g][d0+1]=w1; s_wf[g][d0+2]=w2; s_wf[g][d0+3]=w3;
    }
    __syncthreads();

    // ---- o[g][h=t] = sum_d wf[g][d] * Wvp[d][h] ----
    float o0=0.f, o1=0.f, o2=0.f, o3=0.f;
    for (int d4 = 0; d4 < DP/4; ++d4) {
        float4 wf0 = *(const float4*)&s_wf[0][d4*4];
        float4 wf1 = *(const float4*)&s_wf[1][d4*4];
        float4 wf2 = *(const float4*)&s_wf[2][d4*4];
        float4 wf3 = *(const float4*)&s_wf[3][d4*4];
        float v0 = Wvpt[(size_t)(d4*4+0)*CO + t];
        float v1 = Wvpt[(size_t)(d4*4+1)*CO + t];
        float v2 = Wvpt[(size_t)(d4*4+2)*CO + t];
        float v3 = Wvpt[(size_t)(d4*4+3)*CO + t];
        o0=fmaf(wf0.x,v0,o0); o0=fmaf(wf0.y,v1,o0); o0=fmaf(wf0.z,v2,o0); o0=fmaf(wf0.w,v3,o0);
        o1=fmaf(wf1.x,v0,o1); o1=fmaf(wf1.y,v1,o1); o1=fmaf(wf1.z,v2,o1); o1=fmaf(wf1.w,v3,o1);
        o2=fmaf(wf2.x,v0,o2); o2=fmaf(wf2.y,v1,o2); o2=fmaf(wf2.z,v2,o2); o2=fmaf(wf2.w,v3,o2);
        o3=fmaf(wf3.x,v0,o3); o3=fmaf(wf3.y,v1,o3); o3=fmaf(wf3.z,v2,o3); o3=fmaf(wf3.w,v3,o3);
    }
    outp[(size_t)(bs0+0)*CO + t] = o0;
    outp[(size_t)(bs0+1)*CO + t] = o1;
    outp[(size_t)(bs0+2)*CO + t] = o2;
    outp[(size_t)(bs0+3)*CO + t] = o3;
    __syncthreads();
}

__global__ __launch_bounds__(256) void attn_kernel(
    const float* __restrict__ xyz, const float* __restrict__ mad,
    const float* __restrict__ adj, const float* __restrict__ pt,
    const float* __restrict__ mad_fea, const float* __restrict__ adj_fea,
    const float* __restrict__ pt_fea,  const float* __restrict__ cst_fea,
    const float* __restrict__ M, const float* __restrict__ Wvp,
    const int* __restrict__ fps_idx, const int* __restrict__ nbr_idx,
    float* __restrict__ out)
{
    __shared__ float s_cf[4][CIN];
    __shared__ float s_u[4][DP];
    __shared__ float s_fea[4][KNN][DP];
    __shared__ float s_sc[4][KNN];
    __shared__ float s_wf[4][DP];
    __shared__ int   s_nbr4[4][KNN];

    const int bs0 = blockIdx.x * 4;
    const int b   = bs0 >> 10;
    const int t   = threadIdx.x;
    const int g   = t >> 6, l = t & 63;
    const float* xb = xyz + (size_t)b * NPTS * 3;

    const int ci = fps_idx[bs0 + g];      // wave-uniform load
    if (t < 128) s_nbr4[t>>5][t&31] = nbr_idx[(size_t)(bs0 + (t>>5))*KNN + (t&31)];

    // small per-center outputs (wave-private)
    if (l < 3)             out[OFF_CXYZ + (bs0+g)*3 + l]      = xb[(size_t)ci*3 + l];
    if (l >= 4 && l < 7)   out[OFF_CMAD + (bs0+g)*3 + (l-4)]  = mad[(size_t)(b*NPTS+ci)*3 + (l-4)];
    if (l >= 8 && l < 10)  out[OFF_CADJ + (bs0+g)*2 + (l-8)]  = adj[(size_t)(b*NPTS+ci)*2 + (l-8)];
    if (l >= 12 && l < 16) out[OFF_CPT  + (bs0+g)*4 + (l-12)] = pt[(size_t)(b*NPTS+ci)*4 + (l-12)];
    __syncthreads();

    attn_t<0>(b, bs0, ci, mad_fea, mad, M + 0*CIN*DP, Wvp + 0*DP*CO, out + OFF_OMAD,
              s_cf, s_u, s_fea, s_sc, s_wf, s_nbr4);
    attn_t<1>(b, bs0, ci, adj_fea, adj, M + 1*CIN*DP, Wvp + 1*DP*CO, out + OFF_OADJ,
              s_cf, s_u, s_fea, s_sc, s_wf, s_nbr4);
    attn_t<2>(b, bs0, ci, pt_fea,  pt,  M + 2*CIN*DP, Wvp + 2*DP*CO, out + OFF_OPT,
              s_cf, s_u, s_fea, s_sc, s_wf, s_nbr4);
    attn_t<3>(b, bs0, ci, cst_fea, xyz, M + 3*CIN*DP, Wvp + 3*DP*CO, out + OFF_OCST,
              s_cf, s_u, s_fea, s_sc, s_wf, s_nbr4);
}

extern "C" void kernel_launch(void* const* d_in, const int* in_sizes, int n_in,
                              void* d_out, int out_size, void* d_ws, size_t ws_size,
                              hipStream_t stream)
{
    const float* xyz     = (const float*)d_in[0];
    const float* mad     = (const float*)d_in[1];
    const float* adj     = (const float*)d_in[2];
    const float* pt      = (const float*)d_in[3];
    const float* mad_fea = (const float*)d_in[4];
    const float* adj_fea = (const float*)d_in[5];
    const float* pt_fea  = (const float*)d_in[6];
    const float* cst_fea = (const float*)d_in[7];
    const float* wq_mad  = (const float*)d_in[8];
    const float* wk_mad  = (const float*)d_in[9];
    const float* wv_mad  = (const float*)d_in[10];
    const float* wq_adj  = (const float*)d_in[11];
    const float* wk_adj  = (const float*)d_in[12];
    const float* wv_adj  = (const float*)d_in[13];
    const float* wq_pt   = (const float*)d_in[14];
    const float* wk_pt   = (const float*)d_in[15];
    const float* wv_pt   = (const float*)d_in[16];
    const float* wq_cst  = (const float*)d_in[17];
    const float* wk_cst  = (const float*)d_in[18];
    const float* wv_cst  = (const float*)d_in[19];
    float* out = (float*)d_out;

    int*   fps_idx = (int*)d_ws;                      // 4096 ints
    int*   nbr_idx = fps_idx + BATCH*NC;              // 131072 ints
    float* M       = (float*)(nbr_idx + BATCH*NC*KNN);// 4*128*136 floats
    float* Wvp     = M + 4*CIN*DP;                    // 4*136*256 floats

    fps_prep_kernel<<<BATCH + 4*DP, 512, 0, stream>>>(xyz, fps_idx,
        wq_mad, wk_mad, wv_mad, wq_adj, wk_adj, wv_adj,
        wq_pt, wk_pt, wv_pt, wq_cst, wk_cst, wv_cst, M, Wvp);
    knn_kernel<<<BATCH*NC/4, 256, 0, stream>>>(xyz, fps_idx, nbr_idx);
    attn_kernel<<<BATCH*NC/4, 256, 0, stream>>>(xyz, mad, adj, pt,
        mad_fea, adj_fea, pt_fea, cst_fea, M, Wvp, fps_idx, nbr_idx, out);
}